// Round 1
// baseline (1008.738 us; speedup 1.0000x reference)
//
#include <hip/hip_runtime.h>
#include <cstddef>

#define NN 100000
#define EE 1600000
#define F_IN 128
#define HID 48
#define NCLS 40
#define EPSV 1e-5f
#define SLOPE 0.01f

__device__ inline void fma4(float4& a, float s, const float4 w) {
    a.x += s * w.x; a.y += s * w.y; a.z += s * w.z; a.w += s * w.w;
}

// ---------- edge preprocessing ----------

__global__ void k_edge_deg(const int* __restrict__ ei, const float* __restrict__ ew,
                           float* __restrict__ wdeg, int* __restrict__ cnt) {
    int e = blockIdx.x * 256 + threadIdx.x;
    if (e < EE) {
        int d = ei[EE + e];
        atomicAdd(&wdeg[d], ew[e]);
        atomicAdd(&cnt[d], 1);
    }
}

__global__ void k_dinv(float* __restrict__ dinv, const float* __restrict__ wdeg) {
    int n = blockIdx.x * 256 + threadIdx.x;
    if (n < NN) dinv[n] = rsqrtf(wdeg[n] + 1.0f);   // +1 = self-loop weight; always > 0
}

__global__ void k_scan1(const int* __restrict__ cnt, int* __restrict__ row_start,
                        int* __restrict__ partials) {
    __shared__ int tmp[1024];
    int tid = threadIdx.x;
    int i = blockIdx.x * 1024 + tid;
    int v = (i < NN) ? cnt[i] : 0;
    tmp[tid] = v;
    __syncthreads();
    for (int off = 1; off < 1024; off <<= 1) {
        int t = (tid >= off) ? tmp[tid - off] : 0;
        __syncthreads();
        tmp[tid] += t;
        __syncthreads();
    }
    if (i < NN) row_start[i] = tmp[tid] - v;          // exclusive within block
    if (tid == 1023) partials[blockIdx.x] = tmp[tid]; // block total
}

__global__ void k_scan2(const int* __restrict__ partials, int* __restrict__ p_off, int nb) {
    __shared__ int tmp[128];
    int tid = threadIdx.x;
    int v = (tid < nb) ? partials[tid] : 0;
    tmp[tid] = v;
    __syncthreads();
    for (int off = 1; off < 128; off <<= 1) {
        int t = (tid >= off) ? tmp[tid - off] : 0;
        __syncthreads();
        tmp[tid] += t;
        __syncthreads();
    }
    if (tid < nb) p_off[tid] = tmp[tid] - v;          // exclusive
}

__global__ void k_scan3(int* __restrict__ row_start, int* __restrict__ cursor,
                        const int* __restrict__ p_off) {
    int tid = threadIdx.x;
    int i = blockIdx.x * 1024 + tid;
    if (i < NN) {
        int v = row_start[i] + p_off[blockIdx.x];
        row_start[i] = v;
        cursor[i] = v;
    }
    if (i == 0) row_start[NN] = EE;
}

__global__ void k_scatter(const int* __restrict__ ei, const float* __restrict__ ew,
                          const float* __restrict__ dinv, int* __restrict__ cursor,
                          int* __restrict__ csr_src, float* __restrict__ csr_norm) {
    int e = blockIdx.x * 256 + threadIdx.x;
    if (e < EE) {
        int s = ei[e];
        int d = ei[EE + e];
        int pos = atomicAdd(&cursor[d], 1);
        csr_src[pos] = s;
        csr_norm[pos] = dinv[s] * ew[e] * dinv[d];
    }
}

// ---------- dense layers ----------

// z = lrelu(x @ W_first + b_first)   x:[N,128] W:[128,48]
__global__ __launch_bounds__(256) void k_mm1(const float* __restrict__ x, const float* __restrict__ W,
                                             const float* __restrict__ b, float* __restrict__ z) {
    __shared__ float4 sW4[F_IN * HID / 4];   // 24 KB
    __shared__ float sB[HID];
    int tid = threadIdx.x;
    const float4* W4 = (const float4*)W;
    for (int i = tid; i < F_IN * HID / 4; i += 256) sW4[i] = W4[i];
    if (tid < HID) sB[tid] = b[tid];
    __syncthreads();
    int r = blockIdx.x * 256 + tid;
    if (r >= NN) return;
    float4 acc[12];
#pragma unroll
    for (int j = 0; j < 12; j++) {
        acc[j].x = sB[4 * j]; acc[j].y = sB[4 * j + 1];
        acc[j].z = sB[4 * j + 2]; acc[j].w = sB[4 * j + 3];
    }
    const float4* xr = (const float4*)(x + (size_t)r * F_IN);
    for (int k4 = 0; k4 < F_IN / 4; k4++) {
        float4 xv = xr[k4];
        float xs[4] = {xv.x, xv.y, xv.z, xv.w};
#pragma unroll
        for (int q = 0; q < 4; q++) {
            int k = k4 * 4 + q;
#pragma unroll
            for (int j = 0; j < 12; j++) fma4(acc[j], xs[q], sW4[k * 12 + j]);
        }
    }
    float4* zr = (float4*)(z + (size_t)r * HID);
#pragma unroll
    for (int j = 0; j < 12; j++) {
        float4 v = acc[j];
        v.x = v.x >= 0.f ? v.x : SLOPE * v.x;
        v.y = v.y >= 0.f ? v.y : SLOPE * v.y;
        v.z = v.z >= 0.f ? v.z : SLOPE * v.z;
        v.w = v.w >= 0.f ? v.w : SLOPE * v.w;
        zr[j] = v;
    }
}

// t = h @ W    h:[N,48] W:[48,48]  (no bias/activation)
__global__ __launch_bounds__(256) void k_mm48(const float* __restrict__ h, const float* __restrict__ W,
                                              float* __restrict__ t) {
    __shared__ float4 sW4[HID * HID / 4];    // 9.2 KB
    int tid = threadIdx.x;
    const float4* W4 = (const float4*)W;
    for (int i = tid; i < HID * HID / 4; i += 256) sW4[i] = W4[i];
    __syncthreads();
    int r = blockIdx.x * 256 + tid;
    if (r >= NN) return;
    float4 acc[12];
#pragma unroll
    for (int j = 0; j < 12; j++) acc[j] = make_float4(0.f, 0.f, 0.f, 0.f);
    const float4* hr = (const float4*)(h + (size_t)r * HID);
#pragma unroll 4
    for (int k4 = 0; k4 < 12; k4++) {
        float4 hv = hr[k4];
        float xs[4] = {hv.x, hv.y, hv.z, hv.w};
#pragma unroll
        for (int q = 0; q < 4; q++) {
            int k = k4 * 4 + q;
#pragma unroll
            for (int j = 0; j < 12; j++) fma4(acc[j], xs[q], sW4[k * 12 + j]);
        }
    }
    float4* tr = (float4*)(t + (size_t)r * HID);
#pragma unroll
    for (int j = 0; j < 12; j++) tr[j] = acc[j];
}

// aggregation: z[n] = lrelu( sum_in-edges hw[src]*norm + hw[n]*dinv[n]^2 + bias )
// one wave per destination row; lanes 0..47 = feature columns
__global__ __launch_bounds__(256) void k_agg(const float* __restrict__ hw, const int* __restrict__ row_start,
                                             const int* __restrict__ csr_src, const float* __restrict__ csr_norm,
                                             const float* __restrict__ dinv, const float* __restrict__ bias,
                                             float* __restrict__ z) {
    int wave = blockIdx.x * 4 + (threadIdx.x >> 6);
    int lane = threadIdx.x & 63;
    int n = wave;
    if (n >= NN) return;
    bool act = lane < HID;
    float di = dinv[n];
    float acc = 0.f;
    if (act) acc = hw[(size_t)n * HID + lane] * di * di;   // self loop
    int e0 = row_start[n], e1 = row_start[n + 1];
    for (int e = e0; e < e1; e++) {
        int s = csr_src[e];
        float w = csr_norm[e];
        if (act) acc += hw[(size_t)s * HID + lane] * w;
    }
    if (act) {
        float v = acc + bias[lane];
        v = v >= 0.f ? v : SLOPE * v;
        z[(size_t)n * HID + lane] = v;
    }
}

// ---------- batch norm ----------

__global__ __launch_bounds__(256) void k_stats(const float* __restrict__ z, float* __restrict__ stats) {
    __shared__ float sS[HID], sQ[HID];
    int tid = threadIdx.x;
    if (tid < HID) { sS[tid] = 0.f; sQ[tid] = 0.f; }
    __syncthreads();
    const float4* z4 = (const float4*)z;
    size_t total = (size_t)NN * HID / 4;
    for (size_t i = (size_t)blockIdx.x * 256 + tid; i < total; i += (size_t)gridDim.x * 256) {
        float4 v = z4[i];
        int c = (int)((i * 4) % HID);
        atomicAdd(&sS[c + 0], v.x); atomicAdd(&sQ[c + 0], v.x * v.x);
        atomicAdd(&sS[c + 1], v.y); atomicAdd(&sQ[c + 1], v.y * v.y);
        atomicAdd(&sS[c + 2], v.z); atomicAdd(&sQ[c + 2], v.z * v.z);
        atomicAdd(&sS[c + 3], v.w); atomicAdd(&sQ[c + 3], v.w * v.w);
    }
    __syncthreads();
    if (tid < HID) {
        atomicAdd(&stats[tid], sS[tid]);
        atomicAdd(&stats[HID + tid], sQ[tid]);
    }
}

__global__ void k_bnparam(const float* __restrict__ stats, const float* __restrict__ g,
                          const float* __restrict__ b, float* __restrict__ ac) {
    int j = threadIdx.x;
    if (j < HID) {
        float mean = stats[j] * (1.0f / (float)NN);
        float var = stats[HID + j] * (1.0f / (float)NN) - mean * mean;
        float inv = rsqrtf(var + EPSV);
        float a = g[j] * inv;
        ac[j] = a;
        ac[HID + j] = b[j] - mean * a;
    }
}

__global__ __launch_bounds__(256) void k_norm(const float* __restrict__ z, const float* __restrict__ ac,
                                              float* __restrict__ h) {
    __shared__ float sA[HID], sC[HID];
    int tid = threadIdx.x;
    if (tid < HID) { sA[tid] = ac[tid]; sC[tid] = ac[HID + tid]; }
    __syncthreads();
    size_t i = (size_t)blockIdx.x * 256 + tid;
    size_t total = (size_t)NN * HID / 4;
    if (i >= total) return;
    float4 v = ((const float4*)z)[i];
    int c = (int)((i * 4) % HID);
    v.x = sA[c + 0] * v.x + sC[c + 0];
    v.y = sA[c + 1] * v.y + sC[c + 1];
    v.z = sA[c + 2] * v.z + sC[c + 2];
    v.w = sA[c + 3] * v.w + sC[c + 3];
    ((float4*)h)[i] = v;
}

// ---------- output layer ----------

__global__ __launch_bounds__(256) void k_final(const float* __restrict__ h0, const float* __restrict__ h1,
                                               const float* __restrict__ h2, const float* __restrict__ W,
                                               const float* __restrict__ b, float* __restrict__ out) {
    __shared__ float4 sW4[3 * HID * NCLS / 4];   // 23 KB
    __shared__ float sB[NCLS];
    int tid = threadIdx.x;
    const float4* W4 = (const float4*)W;
    for (int i = tid; i < 3 * HID * NCLS / 4; i += 256) sW4[i] = W4[i];
    if (tid < NCLS) sB[tid] = b[tid];
    __syncthreads();
    int r = blockIdx.x * 256 + tid;
    if (r >= NN) return;
    float4 acc[10];
#pragma unroll
    for (int j = 0; j < 10; j++) {
        acc[j].x = sB[4 * j]; acc[j].y = sB[4 * j + 1];
        acc[j].z = sB[4 * j + 2]; acc[j].w = sB[4 * j + 3];
    }
    const float* hs[3] = {h0, h1, h2};
#pragma unroll
    for (int part = 0; part < 3; part++) {
        const float4* hr = (const float4*)(hs[part] + (size_t)r * HID);
        for (int k4 = 0; k4 < 12; k4++) {
            float4 hv = hr[k4];
            float xs[4] = {hv.x, hv.y, hv.z, hv.w};
#pragma unroll
            for (int q = 0; q < 4; q++) {
                int k = part * HID + k4 * 4 + q;
#pragma unroll
                for (int j = 0; j < 10; j++) fma4(acc[j], xs[q], sW4[k * 10 + j]);
            }
        }
    }
    float m = -1e30f;
#pragma unroll
    for (int j = 0; j < 10; j++)
        m = fmaxf(m, fmaxf(fmaxf(acc[j].x, acc[j].y), fmaxf(acc[j].z, acc[j].w)));
    float s = 0.f;
#pragma unroll
    for (int j = 0; j < 10; j++)
        s += expf(acc[j].x - m) + expf(acc[j].y - m) + expf(acc[j].z - m) + expf(acc[j].w - m);
    float l = m + logf(s);
    float4* orow = (float4*)(out + (size_t)r * NCLS);
#pragma unroll
    for (int j = 0; j < 10; j++) {
        float4 v = acc[j];
        v.x -= l; v.y -= l; v.z -= l; v.w -= l;
        orow[j] = v;
    }
}

// ---------- launch ----------

extern "C" void kernel_launch(void* const* d_in, const int* in_sizes, int n_in,
                              void* d_out, int out_size, void* d_ws, size_t ws_size,
                              hipStream_t stream) {
    const float* x       = (const float*)d_in[0];
    const int*   ei      = (const int*)d_in[1];     // [2,E] int32
    const float* ew      = (const float*)d_in[2];
    const float* W_first = (const float*)d_in[3];
    const float* b_first = (const float*)d_in[4];
    const float* bn1_g   = (const float*)d_in[5];
    const float* bn1_b   = (const float*)d_in[6];
    const float* Wc1     = (const float*)d_in[7];
    const float* bc1     = (const float*)d_in[8];
    const float* bn2_g   = (const float*)d_in[9];
    const float* bn2_b   = (const float*)d_in[10];
    const float* Wc2     = (const float*)d_in[11];
    const float* bc2     = (const float*)d_in[12];
    const float* bn3_g   = (const float*)d_in[13];
    const float* bn3_b   = (const float*)d_in[14];
    const float* W_out   = (const float*)d_in[15];
    const float* b_out   = (const float*)d_in[16];
    float* out = (float*)d_out;

    // workspace layout
    float* wsf = (float*)d_ws;
    float* h0       = wsf;                                 // N*48
    float* h1       = h0 + (size_t)NN * HID;               // N*48
    float* h2       = h1 + (size_t)NN * HID;               // N*48
    float* zb       = h2 + (size_t)NN * HID;               // N*48 (reused x3)
    float* tb       = zb + (size_t)NN * HID;               // N*48 (hw buffer)
    float* dinv     = tb + (size_t)NN * HID;               // N
    float* wdeg     = dinv + NN;                           // N
    int*   cnt      = (int*)(wdeg + NN);                   // N
    int*   row_st   = cnt + NN;                            // N+1
    int*   cursor   = row_st + NN + 1;                     // N
    int*   csr_src  = cursor + NN;                         // E
    float* csr_nrm  = (float*)(csr_src + EE);              // E
    float* stats    = csr_nrm + EE;                        // 3*96
    float* ac       = stats + 288;                         // 96
    int*   partials = (int*)(ac + 96);                     // 128
    int*   p_off    = partials + 128;                      // 128

    const int nb_scan = (NN + 1023) / 1024;                // 98
    const int blkN = (NN + 255) / 256;                     // 391
    const int blkE = (EE + 255) / 256;
    const int blkNorm = (int)(((size_t)NN * HID / 4 + 255) / 256);

    // zero what must be zero (ws is poisoned 0xAA)
    hipMemsetAsync(wdeg, 0, sizeof(float) * NN + sizeof(int) * NN, stream);  // wdeg + cnt
    hipMemsetAsync(stats, 0, sizeof(float) * 288, stream);

    // graph preprocessing (shared by both convs)
    k_edge_deg<<<blkE, 256, 0, stream>>>(ei, ew, wdeg, cnt);
    k_dinv<<<blkN, 256, 0, stream>>>(dinv, wdeg);
    k_scan1<<<nb_scan, 1024, 0, stream>>>(cnt, row_st, partials);
    k_scan2<<<1, 128, 0, stream>>>(partials, p_off, nb_scan);
    k_scan3<<<nb_scan, 1024, 0, stream>>>(row_st, cursor, p_off);
    k_scatter<<<blkE, 256, 0, stream>>>(ei, ew, dinv, cursor, csr_src, csr_nrm);

    // layer 1: z = lrelu(x@W_first + b); BN -> h0
    k_mm1<<<blkN, 256, 0, stream>>>(x, W_first, b_first, zb);
    k_stats<<<512, 256, 0, stream>>>(zb, stats);
    k_bnparam<<<1, 64, 0, stream>>>(stats, bn1_g, bn1_b, ac);
    k_norm<<<blkNorm, 256, 0, stream>>>(zb, ac, h0);

    // conv 1
    k_mm48<<<blkN, 256, 0, stream>>>(h0, Wc1, tb);
    k_agg<<<(NN + 3) / 4, 256, 0, stream>>>(tb, row_st, csr_src, csr_nrm, dinv, bc1, zb);
    k_stats<<<512, 256, 0, stream>>>(zb, stats + 96);
    k_bnparam<<<1, 64, 0, stream>>>(stats + 96, bn2_g, bn2_b, ac);
    k_norm<<<blkNorm, 256, 0, stream>>>(zb, ac, h1);

    // conv 2
    k_mm48<<<blkN, 256, 0, stream>>>(h1, Wc2, tb);
    k_agg<<<(NN + 3) / 4, 256, 0, stream>>>(tb, row_st, csr_src, csr_nrm, dinv, bc2, zb);
    k_stats<<<512, 256, 0, stream>>>(zb, stats + 192);
    k_bnparam<<<1, 64, 0, stream>>>(stats + 192, bn3_g, bn3_b, ac);
    k_norm<<<blkNorm, 256, 0, stream>>>(zb, ac, h2);

    // output layer + log_softmax
    k_final<<<blkN, 256, 0, stream>>>(h0, h1, h2, W_out, b_out, out);
}

// Round 2
// 715.072 us; speedup vs baseline: 1.4107x; 1.4107x over previous
//
#include <hip/hip_runtime.h>
#include <cstddef>

#define NN 100000
#define EE 1600000
#define F_IN 128
#define HID 48
#define NCLS 40
#define EPSV 1e-5f
#define SLOPE 0.01f

__device__ inline void fma4(float4& a, float s, const float4 w) {
    a.x += s * w.x; a.y += s * w.y; a.z += s * w.z; a.w += s * w.w;
}

// ---------- edge preprocessing ----------

__global__ void k_edge_deg(const int* __restrict__ ei, const float* __restrict__ ew,
                           float* __restrict__ wdeg, int* __restrict__ cnt) {
    int e = blockIdx.x * 256 + threadIdx.x;
    if (e < EE) {
        int d = ei[EE + e];
        atomicAdd(&wdeg[d], ew[e]);
        atomicAdd(&cnt[d], 1);
    }
}

__global__ void k_dinv(float* __restrict__ dinv, const float* __restrict__ wdeg) {
    int n = blockIdx.x * 256 + threadIdx.x;
    if (n < NN) dinv[n] = rsqrtf(wdeg[n] + 1.0f);   // +1 = self-loop weight; always > 0
}

__global__ void k_scan1(const int* __restrict__ cnt, int* __restrict__ row_start,
                        int* __restrict__ partials) {
    __shared__ int tmp[1024];
    int tid = threadIdx.x;
    int i = blockIdx.x * 1024 + tid;
    int v = (i < NN) ? cnt[i] : 0;
    tmp[tid] = v;
    __syncthreads();
    for (int off = 1; off < 1024; off <<= 1) {
        int t = (tid >= off) ? tmp[tid - off] : 0;
        __syncthreads();
        tmp[tid] += t;
        __syncthreads();
    }
    if (i < NN) row_start[i] = tmp[tid] - v;
    if (tid == 1023) partials[blockIdx.x] = tmp[tid];
}

__global__ void k_scan2(const int* __restrict__ partials, int* __restrict__ p_off, int nb) {
    __shared__ int tmp[128];
    int tid = threadIdx.x;
    int v = (tid < nb) ? partials[tid] : 0;
    tmp[tid] = v;
    __syncthreads();
    for (int off = 1; off < 128; off <<= 1) {
        int t = (tid >= off) ? tmp[tid - off] : 0;
        __syncthreads();
        tmp[tid] += t;
        __syncthreads();
    }
    if (tid < nb) p_off[tid] = tmp[tid] - v;
}

__global__ void k_scan3(int* __restrict__ row_start, int* __restrict__ cursor,
                        const int* __restrict__ p_off) {
    int tid = threadIdx.x;
    int i = blockIdx.x * 1024 + tid;
    if (i < NN) {
        int v = row_start[i] + p_off[blockIdx.x];
        row_start[i] = v;
        cursor[i] = v;
    }
    if (i == 0) row_start[NN] = EE;
}

// pack (src, norm) into one float2 per edge
__global__ void k_scatter(const int* __restrict__ ei, const float* __restrict__ ew,
                          const float* __restrict__ dinv, int* __restrict__ cursor,
                          float2* __restrict__ es) {
    int e = blockIdx.x * 256 + threadIdx.x;
    if (e < EE) {
        int s = ei[e];
        int d = ei[EE + e];
        int pos = atomicAdd(&cursor[d], 1);
        es[pos] = make_float2(__int_as_float(s), dinv[s] * ew[e] * dinv[d]);
    }
}

// ---------- dense layers ----------

// z = lrelu(x @ W_first + b_first)   x:[N,128] W:[128,48]
__global__ __launch_bounds__(256) void k_mm1(const float* __restrict__ x, const float* __restrict__ W,
                                             const float* __restrict__ b, float* __restrict__ z) {
    __shared__ float4 sW4[F_IN * HID / 4];   // 24 KB
    __shared__ float sB[HID];
    int tid = threadIdx.x;
    const float4* W4 = (const float4*)W;
    for (int i = tid; i < F_IN * HID / 4; i += 256) sW4[i] = W4[i];
    if (tid < HID) sB[tid] = b[tid];
    __syncthreads();
    int r = blockIdx.x * 256 + tid;
    if (r >= NN) return;
    float4 acc[12];
#pragma unroll
    for (int j = 0; j < 12; j++) {
        acc[j].x = sB[4 * j]; acc[j].y = sB[4 * j + 1];
        acc[j].z = sB[4 * j + 2]; acc[j].w = sB[4 * j + 3];
    }
    const float4* xr = (const float4*)(x + (size_t)r * F_IN);
    for (int k4 = 0; k4 < F_IN / 4; k4++) {
        float4 xv = xr[k4];
        float xs[4] = {xv.x, xv.y, xv.z, xv.w};
#pragma unroll
        for (int q = 0; q < 4; q++) {
            int k = k4 * 4 + q;
#pragma unroll
            for (int j = 0; j < 12; j++) fma4(acc[j], xs[q], sW4[k * 12 + j]);
        }
    }
    float4* zr = (float4*)(z + (size_t)r * HID);
#pragma unroll
    for (int j = 0; j < 12; j++) {
        float4 v = acc[j];
        v.x = v.x >= 0.f ? v.x : SLOPE * v.x;
        v.y = v.y >= 0.f ? v.y : SLOPE * v.y;
        v.z = v.z >= 0.f ? v.z : SLOPE * v.z;
        v.w = v.w >= 0.f ? v.w : SLOPE * v.w;
        zr[j] = v;
    }
}

// t = z @ Wp + rc   (BN affine folded into Wp/rc; z:[N,48] raw pre-BN)
__global__ __launch_bounds__(256) void k_mm48(const float* __restrict__ z, const float* __restrict__ Wp,
                                              const float* __restrict__ rc, float* __restrict__ t) {
    __shared__ float4 sW4[HID * HID / 4];    // 9.2 KB
    __shared__ float sR[HID];
    int tid = threadIdx.x;
    const float4* W4 = (const float4*)Wp;
    for (int i = tid; i < HID * HID / 4; i += 256) sW4[i] = W4[i];
    if (tid < HID) sR[tid] = rc[tid];
    __syncthreads();
    int r = blockIdx.x * 256 + tid;
    if (r >= NN) return;
    float4 acc[12];
#pragma unroll
    for (int j = 0; j < 12; j++) {
        acc[j].x = sR[4 * j]; acc[j].y = sR[4 * j + 1];
        acc[j].z = sR[4 * j + 2]; acc[j].w = sR[4 * j + 3];
    }
    const float4* hr = (const float4*)(z + (size_t)r * HID);
#pragma unroll 4
    for (int k4 = 0; k4 < 12; k4++) {
        float4 hv = hr[k4];
        float xs[4] = {hv.x, hv.y, hv.z, hv.w};
#pragma unroll
        for (int q = 0; q < 4; q++) {
            int k = k4 * 4 + q;
#pragma unroll
            for (int j = 0; j < 12; j++) fma4(acc[j], xs[q], sW4[k * 12 + j]);
        }
    }
    float4* tr = (float4*)(t + (size_t)r * HID);
#pragma unroll
    for (int j = 0; j < 12; j++) tr[j] = acc[j];
}

// aggregation: z[n] = lrelu( sum_in-edges hw[src]*norm + hw[n]*dinv[n]^2 + bias )
// one wave per dst row; 4 groups of 16 lanes each handle one edge; 12 lanes/group do float4
__global__ __launch_bounds__(256) void k_agg(const float4* __restrict__ hw4, const int* __restrict__ row_start,
                                             const float2* __restrict__ es, const float* __restrict__ dinv,
                                             const float* __restrict__ bias, float4* __restrict__ z4) {
    int n = blockIdx.x * 4 + (threadIdx.x >> 6);
    int lane = threadIdx.x & 63;
    int g = lane >> 4, sub = lane & 15;
    bool act = sub < 12;
    float4 acc = make_float4(0.f, 0.f, 0.f, 0.f);
    if (g == 0 && act) {
        float di = dinv[n];
        float w = di * di;
        float4 v = hw4[(size_t)n * 12 + sub];
        acc.x = w * v.x; acc.y = w * v.y; acc.z = w * v.z; acc.w = w * v.w;
    }
    int e0 = row_start[n], e1 = row_start[n + 1];
    int eg = e0 + g;
    float2 meta = (eg < e1) ? es[eg] : make_float2(0.f, 0.f);
    for (int e = e0; e < e1; e += 4) {
        float2 cur = meta;
        int egn = e + 4 + g;
        meta = (egn < e1) ? es[egn] : make_float2(0.f, 0.f);
        if (e + g < e1 && act) {
            int s = __float_as_int(cur.x);
            float w = cur.y;
            float4 v = hw4[(size_t)s * 12 + sub];
            acc.x += w * v.x; acc.y += w * v.y; acc.z += w * v.z; acc.w += w * v.w;
        }
    }
    // reduce across the 4 groups (xor by 16, 32) — all lanes participate
#pragma unroll
    for (int off = 16; off <= 32; off <<= 1) {
        acc.x += __shfl_xor(acc.x, off);
        acc.y += __shfl_xor(acc.y, off);
        acc.z += __shfl_xor(acc.z, off);
        acc.w += __shfl_xor(acc.w, off);
    }
    if (g == 0 && act) {
        const float4* b4 = (const float4*)bias;
        float4 bv = b4[sub];
        float4 v;
        v.x = acc.x + bv.x; v.y = acc.y + bv.y; v.z = acc.z + bv.z; v.w = acc.w + bv.w;
        v.x = v.x >= 0.f ? v.x : SLOPE * v.x;
        v.y = v.y >= 0.f ? v.y : SLOPE * v.y;
        v.z = v.z >= 0.f ? v.z : SLOPE * v.z;
        v.w = v.w >= 0.f ? v.w : SLOPE * v.w;
        z4[(size_t)n * 12 + sub] = v;
    }
}

// ---------- batch norm stats / folding ----------

// wave-per-row register accumulation; lane<48 = column
__global__ __launch_bounds__(256) void k_stats(const float* __restrict__ z, float* __restrict__ stats) {
    __shared__ float sS[HID], sQ[HID];
    int tid = threadIdx.x;
    int wid = tid >> 6, lane = tid & 63;
    if (tid < HID) { sS[tid] = 0.f; sQ[tid] = 0.f; }
    __syncthreads();
    if (lane < HID) {
        float s = 0.f, q = 0.f;
        for (int r = blockIdx.x * 4 + wid; r < NN; r += gridDim.x * 4) {
            float v = z[(size_t)r * HID + lane];
            s += v; q += v * v;
        }
        atomicAdd(&sS[lane], s);   // 4-way contention only
        atomicAdd(&sQ[lane], q);
    }
    __syncthreads();
    if (tid < HID) {
        atomicAdd(&stats[tid], sS[tid]);
        atomicAdd(&stats[HID + tid], sQ[tid]);
    }
}

// compute a,c from stats; fold into W (48x48): Wp[k][j]=a[k]W[k][j], rc[j]=sum_k c[k]W[k][j]
__global__ __launch_bounds__(256) void k_bn_fold(const float* __restrict__ stats, const float* __restrict__ g,
                                                 const float* __restrict__ b, const float* __restrict__ W,
                                                 float* __restrict__ ac, float* __restrict__ Wp,
                                                 float* __restrict__ rc) {
    __shared__ float sA[HID], sC[HID];
    int tid = threadIdx.x;
    if (tid < HID) {
        float mean = stats[tid] * (1.0f / (float)NN);
        float var = stats[HID + tid] * (1.0f / (float)NN) - mean * mean;
        float a = g[tid] * rsqrtf(var + EPSV);
        float c = b[tid] - mean * a;
        sA[tid] = a; sC[tid] = c;
        ac[tid] = a; ac[HID + tid] = c;
    }
    __syncthreads();
    for (int i = tid; i < HID * HID; i += 256) Wp[i] = sA[i / HID] * W[i];
    if (tid < HID) {
        float acc = 0.f;
        for (int k = 0; k < HID; k++) acc += sC[k] * W[k * HID + tid];
        rc[tid] = acc;
    }
}

// layer-3 BN: only a,c needed (consumed by final fold)
__global__ void k_bnparam(const float* __restrict__ stats, const float* __restrict__ g,
                          const float* __restrict__ b, float* __restrict__ ac) {
    int j = threadIdx.x;
    if (j < HID) {
        float mean = stats[j] * (1.0f / (float)NN);
        float var = stats[HID + j] * (1.0f / (float)NN) - mean * mean;
        float a = g[j] * rsqrtf(var + EPSV);
        ac[j] = a;
        ac[HID + j] = b[j] - mean * a;
    }
}

// fold all three BN affines into W_out: Wp[144][40], bc[40]
__global__ __launch_bounds__(256) void k_fold_final(const float* __restrict__ ac0, const float* __restrict__ ac1,
                                                    const float* __restrict__ ac2, const float* __restrict__ W,
                                                    const float* __restrict__ b, float* __restrict__ Wp,
                                                    float* __restrict__ bc) {
    __shared__ float sA[3 * HID], sC[3 * HID];
    int tid = threadIdx.x;
    if (tid < 3 * HID) {
        const float* a = (tid < HID) ? ac0 : (tid < 2 * HID) ? ac1 : ac2;
        int j = tid % HID;
        sA[tid] = a[j]; sC[tid] = a[HID + j];
    }
    __syncthreads();
    for (int i = tid; i < 3 * HID * NCLS; i += 256) Wp[i] = sA[i / NCLS] * W[i];
    if (tid < NCLS) {
        float acc = b[tid];
        for (int k = 0; k < 3 * HID; k++) acc += sC[k] * W[k * NCLS + tid];
        bc[tid] = acc;
    }
}

// ---------- output layer (reads raw z0,z1,z2; BN folded into Wp/bc) ----------

__global__ __launch_bounds__(256) void k_final(const float* __restrict__ z0, const float* __restrict__ z1,
                                               const float* __restrict__ z2, const float* __restrict__ Wp,
                                               const float* __restrict__ bc, float* __restrict__ out) {
    __shared__ float4 sW4[3 * HID * NCLS / 4];   // 23 KB
    __shared__ float sB[NCLS];
    int tid = threadIdx.x;
    const float4* W4 = (const float4*)Wp;
    for (int i = tid; i < 3 * HID * NCLS / 4; i += 256) sW4[i] = W4[i];
    if (tid < NCLS) sB[tid] = bc[tid];
    __syncthreads();
    int r = blockIdx.x * 256 + tid;
    if (r >= NN) return;
    float4 acc[10];
#pragma unroll
    for (int j = 0; j < 10; j++) {
        acc[j].x = sB[4 * j]; acc[j].y = sB[4 * j + 1];
        acc[j].z = sB[4 * j + 2]; acc[j].w = sB[4 * j + 3];
    }
    const float* zs[3] = {z0, z1, z2};
#pragma unroll
    for (int part = 0; part < 3; part++) {
        const float4* hr = (const float4*)(zs[part] + (size_t)r * HID);
        for (int k4 = 0; k4 < 12; k4++) {
            float4 hv = hr[k4];
            float xs[4] = {hv.x, hv.y, hv.z, hv.w};
#pragma unroll
            for (int q = 0; q < 4; q++) {
                int k = part * HID + k4 * 4 + q;
#pragma unroll
                for (int j = 0; j < 10; j++) fma4(acc[j], xs[q], sW4[k * 10 + j]);
            }
        }
    }
    float m = -1e30f;
#pragma unroll
    for (int j = 0; j < 10; j++)
        m = fmaxf(m, fmaxf(fmaxf(acc[j].x, acc[j].y), fmaxf(acc[j].z, acc[j].w)));
    float s = 0.f;
#pragma unroll
    for (int j = 0; j < 10; j++)
        s += __expf(acc[j].x - m) + __expf(acc[j].y - m) + __expf(acc[j].z - m) + __expf(acc[j].w - m);
    float l = m + __logf(s);
    float4* orow = (float4*)(out + (size_t)r * NCLS);
#pragma unroll
    for (int j = 0; j < 10; j++) {
        float4 v = acc[j];
        v.x -= l; v.y -= l; v.z -= l; v.w -= l;
        orow[j] = v;
    }
}

// ---------- launch ----------

extern "C" void kernel_launch(void* const* d_in, const int* in_sizes, int n_in,
                              void* d_out, int out_size, void* d_ws, size_t ws_size,
                              hipStream_t stream) {
    const float* x       = (const float*)d_in[0];
    const int*   ei      = (const int*)d_in[1];
    const float* ew      = (const float*)d_in[2];
    const float* W_first = (const float*)d_in[3];
    const float* b_first = (const float*)d_in[4];
    const float* bn1_g   = (const float*)d_in[5];
    const float* bn1_b   = (const float*)d_in[6];
    const float* Wc1     = (const float*)d_in[7];
    const float* bc1     = (const float*)d_in[8];
    const float* bn2_g   = (const float*)d_in[9];
    const float* bn2_b   = (const float*)d_in[10];
    const float* Wc2     = (const float*)d_in[11];
    const float* bc2     = (const float*)d_in[12];
    const float* bn3_g   = (const float*)d_in[13];
    const float* bn3_b   = (const float*)d_in[14];
    const float* W_out   = (const float*)d_in[15];
    const float* b_out   = (const float*)d_in[16];
    float* out = (float*)d_out;

    // workspace layout (all 16B-aligned offsets)
    float* wsf = (float*)d_ws;
    float* z0      = wsf;                                  // N*48
    float* z1      = z0 + (size_t)NN * HID;
    float* z2      = z1 + (size_t)NN * HID;
    float* tb      = z2 + (size_t)NN * HID;
    float* dinv    = tb + (size_t)NN * HID;                // N
    float* wdeg    = dinv + NN;                            // N
    int*   cnt     = (int*)(wdeg + NN);                    // N
    int*   row_st  = cnt + NN;                             // N+1 (padded to N+4)
    int*   cursor  = row_st + NN + 4;                      // N
    float2* es     = (float2*)(cursor + NN);               // E float2
    float* stats   = (float*)(es + EE);                    // 3*96
    float* ac      = stats + 288;                          // 3*96
    float* Wp1     = ac + 288;                             // 2304
    float* rc1     = Wp1 + HID * HID;                      // 48
    float* Wp2     = rc1 + HID;                            // 2304
    float* rc2     = Wp2 + HID * HID;                      // 48
    float* WpO     = rc2 + HID;                            // 5760
    float* bcO     = WpO + 3 * HID * NCLS;                 // 40 (+pad)
    int*   partials = (int*)(bcO + 40 + 8);                // 128
    int*   p_off   = partials + 128;                       // 128

    const int nb_scan = (NN + 1023) / 1024;
    const int blkN = (NN + 255) / 256;
    const int blkE = (EE + 255) / 256;

    hipMemsetAsync(wdeg, 0, sizeof(float) * NN + sizeof(int) * NN, stream);  // wdeg + cnt
    hipMemsetAsync(stats, 0, sizeof(float) * 288, stream);

    // CSR build (shared by both convs)
    k_edge_deg<<<blkE, 256, 0, stream>>>(ei, ew, wdeg, cnt);
    k_dinv<<<blkN, 256, 0, stream>>>(dinv, wdeg);
    k_scan1<<<nb_scan, 1024, 0, stream>>>(cnt, row_st, partials);
    k_scan2<<<1, 128, 0, stream>>>(partials, p_off, nb_scan);
    k_scan3<<<nb_scan, 1024, 0, stream>>>(row_st, cursor, p_off);
    k_scatter<<<blkE, 256, 0, stream>>>(ei, ew, dinv, cursor, es);

    // layer 1
    k_mm1<<<blkN, 256, 0, stream>>>(x, W_first, b_first, z0);
    k_stats<<<256, 256, 0, stream>>>(z0, stats);
    k_bn_fold<<<1, 256, 0, stream>>>(stats, bn1_g, bn1_b, Wc1, ac, Wp1, rc1);

    // conv 1
    k_mm48<<<blkN, 256, 0, stream>>>(z0, Wp1, rc1, tb);
    k_agg<<<NN / 4, 256, 0, stream>>>((const float4*)tb, row_st, es, dinv, bc1, (float4*)z1);
    k_stats<<<256, 256, 0, stream>>>(z1, stats + 96);
    k_bn_fold<<<1, 256, 0, stream>>>(stats + 96, bn2_g, bn2_b, Wc2, ac + 96, Wp2, rc2);

    // conv 2
    k_mm48<<<blkN, 256, 0, stream>>>(z1, Wp2, rc2, tb);
    k_agg<<<NN / 4, 256, 0, stream>>>((const float4*)tb, row_st, es, dinv, bc2, (float4*)z2);
    k_stats<<<256, 256, 0, stream>>>(z2, stats + 192);
    k_bnparam<<<1, 64, 0, stream>>>(stats + 192, bn3_g, bn3_b, ac + 192);

    // fold BN1/2/3 into output weights; final layer + log_softmax
    k_fold_final<<<1, 256, 0, stream>>>(ac, ac + 96, ac + 192, W_out, b_out, WpO, bcO);
    k_final<<<blkN, 256, 0, stream>>>(z0, z1, z2, WpO, bcO, out);
}

// Round 3
// 582.500 us; speedup vs baseline: 1.7317x; 1.2276x over previous
//
#include <hip/hip_runtime.h>
#include <cstddef>

#define NN 100000
#define EE 1600000
#define F_IN 128
#define HID 48
#define NCLS 40
#define EPSV 1e-5f
#define SLOPE 0.01f
#define FIXP 16777216.0f   // 2^24 fixed-point scale for edge weights

typedef _Float16 half4 __attribute__((ext_vector_type(4)));

__device__ inline void fma4(float4& a, float s, const float4 w) {
    a.x += s * w.x; a.y += s * w.y; a.z += s * w.z; a.w += s * w.w;
}

// ---------- edge preprocessing ----------

// ONE u64 atomic per edge: high32 = count, low32 = fixed-point weight sum.
// Returned old count = this edge's rank within its destination row.
__global__ void k_edge_deg(const int* __restrict__ ei, const float* __restrict__ ew,
                           unsigned long long* __restrict__ packed, int* __restrict__ rank) {
    int e = blockIdx.x * 256 + threadIdx.x;
    if (e < EE) {
        int d = ei[EE + e];
        unsigned long long add = (1ULL << 32) | (unsigned long long)__float2uint_rn(ew[e] * FIXP);
        unsigned long long old = atomicAdd(&packed[d], add);
        rank[e] = (int)(old >> 32);
    }
}

__global__ void k_dinv(float* __restrict__ dinv, const unsigned long long* __restrict__ packed) {
    int n = blockIdx.x * 256 + threadIdx.x;
    if (n < NN) {
        float wdeg = (float)(unsigned int)(packed[n] & 0xffffffffULL) * (1.0f / FIXP);
        dinv[n] = rsqrtf(wdeg + 1.0f);   // +1 = self-loop weight; always > 0
    }
}

__global__ void k_scan1(const unsigned long long* __restrict__ packed, int* __restrict__ row_start,
                        int* __restrict__ partials) {
    __shared__ int tmp[1024];
    int tid = threadIdx.x;
    int i = blockIdx.x * 1024 + tid;
    int v = (i < NN) ? (int)(packed[i] >> 32) : 0;
    tmp[tid] = v;
    __syncthreads();
    for (int off = 1; off < 1024; off <<= 1) {
        int t = (tid >= off) ? tmp[tid - off] : 0;
        __syncthreads();
        tmp[tid] += t;
        __syncthreads();
    }
    if (i < NN) row_start[i] = tmp[tid] - v;
    if (tid == 1023) partials[blockIdx.x] = tmp[tid];
}

__global__ void k_scan2(const int* __restrict__ partials, int* __restrict__ p_off, int nb) {
    __shared__ int tmp[128];
    int tid = threadIdx.x;
    int v = (tid < nb) ? partials[tid] : 0;
    tmp[tid] = v;
    __syncthreads();
    for (int off = 1; off < 128; off <<= 1) {
        int t = (tid >= off) ? tmp[tid - off] : 0;
        __syncthreads();
        tmp[tid] += t;
        __syncthreads();
    }
    if (tid < nb) p_off[tid] = tmp[tid] - v;
}

__global__ void k_scan3(int* __restrict__ row_start, const int* __restrict__ p_off) {
    int tid = threadIdx.x;
    int i = blockIdx.x * 1024 + tid;
    if (i < NN) row_start[i] += p_off[blockIdx.x];
    if (i == 0) row_start[NN] = EE;
}

// atomic-free scatter: pos = row_start[d] + rank[e]
__global__ void k_scatter(const int* __restrict__ ei, const float* __restrict__ ew,
                          const float* __restrict__ dinv, const int* __restrict__ row_start,
                          const int* __restrict__ rank, float2* __restrict__ es) {
    int e = blockIdx.x * 256 + threadIdx.x;
    if (e < EE) {
        int s = ei[e];
        int d = ei[EE + e];
        int pos = row_start[d] + rank[e];
        es[pos] = make_float2(__int_as_float(s), dinv[s] * ew[e] * dinv[d]);
    }
}

// ---------- dense layers ----------

// z = lrelu(x @ W_first + b_first)   x:[N,128] W:[128,48]
__global__ __launch_bounds__(256) void k_mm1(const float* __restrict__ x, const float* __restrict__ W,
                                             const float* __restrict__ b, float* __restrict__ z) {
    __shared__ float4 sW4[F_IN * HID / 4];   // 24 KB
    __shared__ float sB[HID];
    int tid = threadIdx.x;
    const float4* W4 = (const float4*)W;
    for (int i = tid; i < F_IN * HID / 4; i += 256) sW4[i] = W4[i];
    if (tid < HID) sB[tid] = b[tid];
    __syncthreads();
    int r = blockIdx.x * 256 + tid;
    if (r >= NN) return;
    float4 acc[12];
#pragma unroll
    for (int j = 0; j < 12; j++) {
        acc[j].x = sB[4 * j]; acc[j].y = sB[4 * j + 1];
        acc[j].z = sB[4 * j + 2]; acc[j].w = sB[4 * j + 3];
    }
    const float4* xr = (const float4*)(x + (size_t)r * F_IN);
    for (int k4 = 0; k4 < F_IN / 4; k4++) {
        float4 xv = xr[k4];
        float xs[4] = {xv.x, xv.y, xv.z, xv.w};
#pragma unroll
        for (int q = 0; q < 4; q++) {
            int k = k4 * 4 + q;
#pragma unroll
            for (int j = 0; j < 12; j++) fma4(acc[j], xs[q], sW4[k * 12 + j]);
        }
    }
    float4* zr = (float4*)(z + (size_t)r * HID);
#pragma unroll
    for (int j = 0; j < 12; j++) {
        float4 v = acc[j];
        v.x = v.x >= 0.f ? v.x : SLOPE * v.x;
        v.y = v.y >= 0.f ? v.y : SLOPE * v.y;
        v.z = v.z >= 0.f ? v.z : SLOPE * v.z;
        v.w = v.w >= 0.f ? v.w : SLOPE * v.w;
        zr[j] = v;
    }
}

// t = z @ Wp + rc   (BN affine folded into Wp/rc) — OUTPUT IN FP16 (gather table)
__global__ __launch_bounds__(256) void k_mm48(const float* __restrict__ z, const float* __restrict__ Wp,
                                              const float* __restrict__ rc, half4* __restrict__ t) {
    __shared__ float4 sW4[HID * HID / 4];    // 9.2 KB
    __shared__ float sR[HID];
    int tid = threadIdx.x;
    const float4* W4 = (const float4*)Wp;
    for (int i = tid; i < HID * HID / 4; i += 256) sW4[i] = W4[i];
    if (tid < HID) sR[tid] = rc[tid];
    __syncthreads();
    int r = blockIdx.x * 256 + tid;
    if (r >= NN) return;
    float4 acc[12];
#pragma unroll
    for (int j = 0; j < 12; j++) {
        acc[j].x = sR[4 * j]; acc[j].y = sR[4 * j + 1];
        acc[j].z = sR[4 * j + 2]; acc[j].w = sR[4 * j + 3];
    }
    const float4* hr = (const float4*)(z + (size_t)r * HID);
#pragma unroll 4
    for (int k4 = 0; k4 < 12; k4++) {
        float4 hv = hr[k4];
        float xs[4] = {hv.x, hv.y, hv.z, hv.w};
#pragma unroll
        for (int q = 0; q < 4; q++) {
            int k = k4 * 4 + q;
#pragma unroll
            for (int j = 0; j < 12; j++) fma4(acc[j], xs[q], sW4[k * 12 + j]);
        }
    }
    half4* tr = t + (size_t)r * 12;
#pragma unroll
    for (int j = 0; j < 12; j++) {
        half4 o;
        o.x = (_Float16)acc[j].x; o.y = (_Float16)acc[j].y;
        o.z = (_Float16)acc[j].z; o.w = (_Float16)acc[j].w;
        tr[j] = o;
    }
}

// aggregation: z[n] = lrelu( sum_in-edges hw[src]*norm + hw[n]*dinv[n]^2 + bias )
// one wave per dst row; 4 groups of 16 lanes each handle one edge; 12 lanes/group gather half4
__global__ __launch_bounds__(256) void k_agg(const half4* __restrict__ hw, const int* __restrict__ row_start,
                                             const float2* __restrict__ es, const float* __restrict__ dinv,
                                             const float* __restrict__ bias, float4* __restrict__ z4) {
    int n = blockIdx.x * 4 + (threadIdx.x >> 6);
    int lane = threadIdx.x & 63;
    int g = lane >> 4, sub = lane & 15;
    bool act = sub < 12;
    float4 acc = make_float4(0.f, 0.f, 0.f, 0.f);
    if (g == 0 && act) {
        float di = dinv[n];
        float w = di * di;
        half4 v = hw[(size_t)n * 12 + sub];
        acc.x = w * (float)v.x; acc.y = w * (float)v.y;
        acc.z = w * (float)v.z; acc.w = w * (float)v.w;
    }
    int e0 = row_start[n], e1 = row_start[n + 1];
    int eg = e0 + g;
    float2 meta = (eg < e1) ? es[eg] : make_float2(0.f, 0.f);
    for (int e = e0; e < e1; e += 4) {
        float2 cur = meta;
        int egn = e + 4 + g;
        meta = (egn < e1) ? es[egn] : make_float2(0.f, 0.f);
        if (e + g < e1 && act) {
            int s = __float_as_int(cur.x);
            float w = cur.y;
            half4 v = hw[(size_t)s * 12 + sub];
            acc.x += w * (float)v.x; acc.y += w * (float)v.y;
            acc.z += w * (float)v.z; acc.w += w * (float)v.w;
        }
    }
#pragma unroll
    for (int off = 16; off <= 32; off <<= 1) {
        acc.x += __shfl_xor(acc.x, off);
        acc.y += __shfl_xor(acc.y, off);
        acc.z += __shfl_xor(acc.z, off);
        acc.w += __shfl_xor(acc.w, off);
    }
    if (g == 0 && act) {
        const float4* b4 = (const float4*)bias;
        float4 bv = b4[sub];
        float4 v;
        v.x = acc.x + bv.x; v.y = acc.y + bv.y; v.z = acc.z + bv.z; v.w = acc.w + bv.w;
        v.x = v.x >= 0.f ? v.x : SLOPE * v.x;
        v.y = v.y >= 0.f ? v.y : SLOPE * v.y;
        v.z = v.z >= 0.f ? v.z : SLOPE * v.z;
        v.w = v.w >= 0.f ? v.w : SLOPE * v.w;
        z4[(size_t)n * 12 + sub] = v;
    }
}

// ---------- batch norm stats / folding ----------

__global__ __launch_bounds__(256) void k_stats(const float* __restrict__ z, float* __restrict__ stats) {
    __shared__ float sS[HID], sQ[HID];
    int tid = threadIdx.x;
    int wid = tid >> 6, lane = tid & 63;
    if (tid < HID) { sS[tid] = 0.f; sQ[tid] = 0.f; }
    __syncthreads();
    if (lane < HID) {
        float s = 0.f, q = 0.f;
        for (int r = blockIdx.x * 4 + wid; r < NN; r += gridDim.x * 4) {
            float v = z[(size_t)r * HID + lane];
            s += v; q += v * v;
        }
        atomicAdd(&sS[lane], s);
        atomicAdd(&sQ[lane], q);
    }
    __syncthreads();
    if (tid < HID) {
        atomicAdd(&stats[tid], sS[tid]);
        atomicAdd(&stats[HID + tid], sQ[tid]);
    }
}

__global__ __launch_bounds__(256) void k_bn_fold(const float* __restrict__ stats, const float* __restrict__ g,
                                                 const float* __restrict__ b, const float* __restrict__ W,
                                                 float* __restrict__ ac, float* __restrict__ Wp,
                                                 float* __restrict__ rc) {
    __shared__ float sA[HID], sC[HID];
    int tid = threadIdx.x;
    if (tid < HID) {
        float mean = stats[tid] * (1.0f / (float)NN);
        float var = stats[HID + tid] * (1.0f / (float)NN) - mean * mean;
        float a = g[tid] * rsqrtf(var + EPSV);
        float c = b[tid] - mean * a;
        sA[tid] = a; sC[tid] = c;
        ac[tid] = a; ac[HID + tid] = c;
    }
    __syncthreads();
    for (int i = tid; i < HID * HID; i += 256) Wp[i] = sA[i / HID] * W[i];
    if (tid < HID) {
        float acc = 0.f;
        for (int k = 0; k < HID; k++) acc += sC[k] * W[k * HID + tid];
        rc[tid] = acc;
    }
}

__global__ void k_bnparam(const float* __restrict__ stats, const float* __restrict__ g,
                          const float* __restrict__ b, float* __restrict__ ac) {
    int j = threadIdx.x;
    if (j < HID) {
        float mean = stats[j] * (1.0f / (float)NN);
        float var = stats[HID + j] * (1.0f / (float)NN) - mean * mean;
        float a = g[j] * rsqrtf(var + EPSV);
        ac[j] = a;
        ac[HID + j] = b[j] - mean * a;
    }
}

__global__ __launch_bounds__(256) void k_fold_final(const float* __restrict__ ac0, const float* __restrict__ ac1,
                                                    const float* __restrict__ ac2, const float* __restrict__ W,
                                                    const float* __restrict__ b, float* __restrict__ Wp,
                                                    float* __restrict__ bc) {
    __shared__ float sA[3 * HID], sC[3 * HID];
    int tid = threadIdx.x;
    if (tid < 3 * HID) {
        const float* a = (tid < HID) ? ac0 : (tid < 2 * HID) ? ac1 : ac2;
        int j = tid % HID;
        sA[tid] = a[j]; sC[tid] = a[HID + j];
    }
    __syncthreads();
    for (int i = tid; i < 3 * HID * NCLS; i += 256) Wp[i] = sA[i / NCLS] * W[i];
    if (tid < NCLS) {
        float acc = b[tid];
        for (int k = 0; k < 3 * HID; k++) acc += sC[k] * W[k * NCLS + tid];
        bc[tid] = acc;
    }
}

// ---------- output layer ----------

__global__ __launch_bounds__(256) void k_final(const float* __restrict__ z0, const float* __restrict__ z1,
                                               const float* __restrict__ z2, const float* __restrict__ Wp,
                                               const float* __restrict__ bc, float* __restrict__ out) {
    __shared__ float4 sW4[3 * HID * NCLS / 4];   // 23 KB
    __shared__ float sB[NCLS];
    int tid = threadIdx.x;
    const float4* W4 = (const float4*)Wp;
    for (int i = tid; i < 3 * HID * NCLS / 4; i += 256) sW4[i] = W4[i];
    if (tid < NCLS) sB[tid] = bc[tid];
    __syncthreads();
    int r = blockIdx.x * 256 + tid;
    if (r >= NN) return;
    float4 acc[10];
#pragma unroll
    for (int j = 0; j < 10; j++) {
        acc[j].x = sB[4 * j]; acc[j].y = sB[4 * j + 1];
        acc[j].z = sB[4 * j + 2]; acc[j].w = sB[4 * j + 3];
    }
    const float* zs[3] = {z0, z1, z2};
#pragma unroll
    for (int part = 0; part < 3; part++) {
        const float4* hr = (const float4*)(zs[part] + (size_t)r * HID);
        for (int k4 = 0; k4 < 12; k4++) {
            float4 hv = hr[k4];
            float xs[4] = {hv.x, hv.y, hv.z, hv.w};
#pragma unroll
            for (int q = 0; q < 4; q++) {
                int k = part * HID + k4 * 4 + q;
#pragma unroll
                for (int j = 0; j < 10; j++) fma4(acc[j], xs[q], sW4[k * 10 + j]);
            }
        }
    }
    float m = -1e30f;
#pragma unroll
    for (int j = 0; j < 10; j++)
        m = fmaxf(m, fmaxf(fmaxf(acc[j].x, acc[j].y), fmaxf(acc[j].z, acc[j].w)));
    float s = 0.f;
#pragma unroll
    for (int j = 0; j < 10; j++)
        s += __expf(acc[j].x - m) + __expf(acc[j].y - m) + __expf(acc[j].z - m) + __expf(acc[j].w - m);
    float l = m + __logf(s);
    float4* orow = (float4*)(out + (size_t)r * NCLS);
#pragma unroll
    for (int j = 0; j < 10; j++) {
        float4 v = acc[j];
        v.x -= l; v.y -= l; v.z -= l; v.w -= l;
        orow[j] = v;
    }
}

// ---------- launch ----------

extern "C" void kernel_launch(void* const* d_in, const int* in_sizes, int n_in,
                              void* d_out, int out_size, void* d_ws, size_t ws_size,
                              hipStream_t stream) {
    const float* x       = (const float*)d_in[0];
    const int*   ei      = (const int*)d_in[1];
    const float* ew      = (const float*)d_in[2];
    const float* W_first = (const float*)d_in[3];
    const float* b_first = (const float*)d_in[4];
    const float* bn1_g   = (const float*)d_in[5];
    const float* bn1_b   = (const float*)d_in[6];
    const float* Wc1     = (const float*)d_in[7];
    const float* bc1     = (const float*)d_in[8];
    const float* bn2_g   = (const float*)d_in[9];
    const float* bn2_b   = (const float*)d_in[10];
    const float* Wc2     = (const float*)d_in[11];
    const float* bc2     = (const float*)d_in[12];
    const float* bn3_g   = (const float*)d_in[13];
    const float* bn3_b   = (const float*)d_in[14];
    const float* W_out   = (const float*)d_in[15];
    const float* b_out   = (const float*)d_in[16];
    float* out = (float*)d_out;

    // workspace layout (float offsets all even; u64/float2 regions 8B-aligned)
    float* wsf = (float*)d_ws;
    float* z0      = wsf;                                  // N*48 f
    float* z1      = z0 + (size_t)NN * HID;
    float* z2      = z1 + (size_t)NN * HID;
    half4* tb      = (half4*)(z2 + (size_t)NN * HID);      // N*48 halves = N*24 f
    unsigned long long* packed = (unsigned long long*)((float*)tb + (size_t)NN * HID / 2);  // N u64
    float* dinv    = (float*)(packed + NN);                // N f
    int*   rank    = (int*)(dinv + NN);                    // E i32
    int*   row_st  = rank + EE;                            // N+4 i32
    float2* es     = (float2*)(row_st + NN + 4);           // E float2
    float* stats   = (float*)(es + EE);                    // 3*96
    float* ac      = stats + 288;                          // 3*96
    float* Wp1     = ac + 288;                             // 2304
    float* rc1     = Wp1 + HID * HID;                      // 48
    float* Wp2     = rc1 + HID;                            // 2304
    float* rc2     = Wp2 + HID * HID;                      // 48
    float* WpO     = rc2 + HID;                            // 5760
    float* bcO     = WpO + 3 * HID * NCLS;                 // 40 (+pad)
    int*   partials = (int*)(bcO + 40 + 8);                // 128
    int*   p_off   = partials + 128;                       // 128

    const int nb_scan = (NN + 1023) / 1024;
    const int blkN = (NN + 255) / 256;
    const int blkE = (EE + 255) / 256;

    hipMemsetAsync(packed, 0, sizeof(unsigned long long) * NN, stream);
    hipMemsetAsync(stats, 0, sizeof(float) * 288, stream);

    // CSR build (shared by both convs) — 1.6M atomics total, scatter is atomic-free
    k_edge_deg<<<blkE, 256, 0, stream>>>(ei, ew, packed, rank);
    k_dinv<<<blkN, 256, 0, stream>>>(dinv, packed);
    k_scan1<<<nb_scan, 1024, 0, stream>>>(packed, row_st, partials);
    k_scan2<<<1, 128, 0, stream>>>(partials, p_off, nb_scan);
    k_scan3<<<nb_scan, 1024, 0, stream>>>(row_st, p_off);
    k_scatter<<<blkE, 256, 0, stream>>>(ei, ew, dinv, row_st, rank, es);

    // layer 1
    k_mm1<<<blkN, 256, 0, stream>>>(x, W_first, b_first, z0);
    k_stats<<<256, 256, 0, stream>>>(z0, stats);
    k_bn_fold<<<1, 256, 0, stream>>>(stats, bn1_g, bn1_b, Wc1, ac, Wp1, rc1);

    // conv 1
    k_mm48<<<blkN, 256, 0, stream>>>(z0, Wp1, rc1, tb);
    k_agg<<<NN / 4, 256, 0, stream>>>(tb, row_st, es, dinv, bc1, (float4*)z1);
    k_stats<<<256, 256, 0, stream>>>(z1, stats + 96);
    k_bn_fold<<<1, 256, 0, stream>>>(stats + 96, bn2_g, bn2_b, Wc2, ac + 96, Wp2, rc2);

    // conv 2
    k_mm48<<<blkN, 256, 0, stream>>>(z1, Wp2, rc2, tb);
    k_agg<<<NN / 4, 256, 0, stream>>>(tb, row_st, es, dinv, bc2, (float4*)z2);
    k_stats<<<256, 256, 0, stream>>>(z2, stats + 192);
    k_bnparam<<<1, 64, 0, stream>>>(stats + 192, bn3_g, bn3_b, ac + 192);

    // fold BN1/2/3 into output weights; final layer + log_softmax
    k_fold_final<<<1, 256, 0, stream>>>(ac, ac + 96, ac + 192, W_out, b_out, WpO, bcO);
    k_final<<<blkN, 256, 0, stream>>>(z0, z1, z2, WpO, bcO, out);
}